// Round 12
// baseline (306.647 us; speedup 1.0000x reference)
//
#include <hip/hip_runtime.h>
#include <math.h>

#define NQ 12
#define DEPTH 3
#define FEAT 768
#define NCLS 10
#define NW 8                 // waves per block
#define AMPS 8               // complex amps per thread
#define PI_HALF 1.57079632679489662f

typedef float v2f __attribute__((ext_vector_type(2)));

// ---------- packed complex helpers (VOP3P packed fp32) ----------
__device__ __forceinline__ v2f pk_mul_bl(v2f A, v2f z) {
    v2f d;
    asm("v_pk_mul_f32 %0, %1, %2 op_sel:[0,0] op_sel_hi:[1,0]"
        : "=v"(d) : "v"(A), "v"(z));
    return d;
}
__device__ __forceinline__ void pk_fma_bl(v2f& d, v2f A, v2f z) {
    asm("v_pk_fma_f32 %0, %1, %2, %0 op_sel:[0,0,0] op_sel_hi:[1,0,1]"
        : "+v"(d) : "v"(A), "v"(z));
}
__device__ __forceinline__ void pk_fma_bh(v2f& d, v2f B, v2f z) {
    asm("v_pk_fma_f32 %0, %1, %2, %0 op_sel:[0,1,0] op_sel_hi:[1,1,1]"
        : "+v"(d) : "v"(B), "v"(z));
}
// z' = S*z + P*p (complex): As={sr,si} Bs={-si,sr} Ap={pr,pi} Bp={-pi,pr}
__device__ __forceinline__ v2f cgate(v2f As, v2f Bs, v2f Ap, v2f Bp, v2f z, v2f p) {
    v2f d = pk_mul_bl(As, z);
    pk_fma_bh(d, Bs, z);
    pk_fma_bl(d, Ap, p);
    pk_fma_bh(d, Bp, p);
    return d;
}

// ---------- lane-swap helpers ----------
#define DPPF(v, ctrl) __int_as_float(__builtin_amdgcn_update_dpp(0, __float_as_int(v), (ctrl), 0xF, 0xF, true))

template<int M>
__device__ __forceinline__ float swx(float v) {
    if constexpr (M == 1) {
        return DPPF(v, 0xB1);
    } else if constexpr (M == 2) {
        return DPPF(v, 0x4E);
    } else if constexpr (M == 4) {
        float t = DPPF(v, 0x141);
        return DPPF(t, 0x1B);
    } else if constexpr (M == 8) {
        return DPPF(v, 0x128);
    } else if constexpr (M == 16) {
        return __int_as_float(__builtin_amdgcn_ds_swizzle(__float_as_int(v), 0x401F));
    } else {
        return __shfl_xor(v, 32, 64);
    }
}

template<int M>
__device__ __forceinline__ v2f swx2(v2f z) {
    v2f p;
    p.x = swx<M>(z.x);
    p.y = swx<M>(z.y);
    return p;
}

__device__ __forceinline__ float allred(float v) {
    v += swx<1>(v); v += swx<2>(v); v += swx<4>(v);
    v += swx<8>(v); v += swx<16>(v); v += swx<32>(v);
    return v;
}

// ---------- state layout ----------
// amp index i (bit11..bit0), wire q <-> bit (11-q).
//   wires 0,1,2 -> wave bits (lw: wire0=lw&4, wire1=lw&2, wire2=lw&1)
//   wires 3..8  -> lane bits (wire3=lane&32 ... wire8=lane&1)
//   wires 9..11 -> reg bits  (wire9=j&4, wire10=j&2, wire11=j&1)

template<int JM>
__device__ __forceinline__ void rot_reg(v2f (&z)[AMPS], const v2f* m) {
    const v2f A0 = m[0], B0 = m[1], P0 = m[2], Q0 = m[3];
    const v2f A1 = m[4], B1 = m[5], P1 = m[6], Q1 = m[7];
    #pragma unroll
    for (int j = 0; j < AMPS; ++j) if (!(j & JM)) {
        const int j1 = j | JM;
        v2f z0 = z[j], z1 = z[j1];
        z[j]  = cgate(A0, B0, P0, Q0, z0, z1);
        z[j1] = cgate(A1, B1, P1, Q1, z1, z0);
    }
}

template<int LM>
__device__ __forceinline__ void rot_lane(v2f (&z)[AMPS], const v2f* m, int lane) {
    const bool b = (lane & LM) != 0;
    const v2f As = b ? m[4] : m[0], Bs = b ? m[5] : m[1];
    const v2f Ap = b ? m[6] : m[2], Bp = b ? m[7] : m[3];
    #pragma unroll
    for (int j = 0; j < AMPS; ++j) {
        v2f p = swx2<LM>(z[j]);
        z[j] = cgate(As, Bs, Ap, Bp, z[j], p);
    }
}

// ---------- merged 3-wire wave gate: z = (R0 (x) R1 (x) R2) acting on wave bits,
// with the PREVIOUS layer's cross-wave CNOT permutation folded into the read
// index: z_new[lw][k] = sum_w U[lw][w] * old[w ^ so(k)][k].
// L=0: so=0. L=1: so=(k&1)?4:0 (CNOT 11->0). L=2: so=(k&3)<<1 (CNOT 10->0, 11->1).
template<int L>
__device__ __forceinline__ void wave3(v2f (&z)[AMPS], const v2f (*uAl)[8], const v2f (*uBl)[8],
                                      v2f (*ex)[AMPS][64], int lw, int lane) {
    #pragma unroll
    for (int k = 0; k < AMPS; ++k) ex[lw][k][lane] = z[k];
    __syncthreads();
    {
        const v2f A = uAl[lw][0], B = uBl[lw][0];
        #pragma unroll
        for (int k = 0; k < AMPS; ++k) {
            const int so = (L == 0) ? 0 : (L == 1) ? ((k & 1) ? 4 : 0) : ((k & 3) << 1);
            v2f p = ex[0 ^ so][k][lane];
            z[k] = pk_mul_bl(A, p);
            pk_fma_bh(z[k], B, p);
        }
    }
    #pragma unroll
    for (int ww = 1; ww < 8; ++ww) {
        const v2f A = uAl[lw][ww], B = uBl[lw][ww];
        #pragma unroll
        for (int k = 0; k < AMPS; ++k) {
            const int so = (L == 0) ? 0 : (L == 1) ? ((k & 1) ? 4 : 0) : ((k & 3) << 1);
            v2f p = ex[ww ^ so][k][lane];
            pk_fma_bl(z[k], A, p);
            pk_fma_bh(z[k], B, p);
        }
    }
    __syncthreads();
}

template<int JC, int JT>
__device__ __forceinline__ void cnot_rr(v2f (&z)[AMPS]) {
    #pragma unroll
    for (int j = 0; j < AMPS; ++j) if ((j & JC) && !(j & JT)) {
        const int j1 = j | JT;
        v2f t = z[j]; z[j] = z[j1]; z[j1] = t;
    }
}

template<int LC, int JT>
__device__ __forceinline__ void cnot_lr(v2f (&z)[AMPS], int lane) {
    const bool b = (lane & LC) != 0;
    #pragma unroll
    for (int j = 0; j < AMPS; ++j) if (!(j & JT)) {
        const int j1 = j | JT;
        v2f z0 = z[j], z1 = z[j1];
        z[j]  = b ? z1 : z0;
        z[j1] = b ? z0 : z1;
    }
}

template<int LC, int LT>
__device__ __forceinline__ void cnot_ll(v2f (&z)[AMPS], int lane) {
    const bool b = (lane & LC) != 0;
    #pragma unroll
    for (int j = 0; j < AMPS; ++j) {
        v2f p = swx2<LT>(z[j]);
        z[j] = b ? p : z[j];
    }
}

template<int PC, int LT>
__device__ __forceinline__ void cnot_wl(v2f (&z)[AMPS], int lw) {
    if (lw & PC) {                      // wave-uniform branch
        #pragma unroll
        for (int j = 0; j < AMPS; ++j) z[j] = swx2<LT>(z[j]);
    }
}

// Block = 1 sample, 8 waves x 64 lanes x 8 amps = 4096 amps.
// Wave wires 0-2 handled by ONE merged 8x8 kron gate per layer (wave3),
// cross-wave CNOT exchanges folded into the next layer's read permutation,
// layer-2 CNOT ring absorbed into Heisenberg-conjugated observables.
__global__ __launch_bounds__(512) void qcircuit_k8(
    const float* __restrict__ x,    // [B, 768]
    const float* __restrict__ Wp,   // [12, 768]
    const float* __restrict__ w,    // [3, 12, 3]
    const float* __restrict__ Wo,   // [10, 12]
    const float* __restrict__ bo,   // [10]
    float* __restrict__ out)        // [B, 10]
{
    const int t = threadIdx.x;
    const int wave = t >> 6;
    const int lane = t & 63;
    const int b = blockIdx.x;

    __shared__ v2f mcoef[DEPTH * NQ][8];   // packed per-wire gate coefficients (lane/reg wires)
    __shared__ v2f uA[DEPTH][8][8], uB[DEPTH][8][8];  // merged 8x8 wave-gate coeffs
    __shared__ v2f ex[NW][AMPS][64];       // 32 KB cross-wave exchange
    __shared__ float red[NW][NQ];
    __shared__ float sh_dot[NQ];
    __shared__ float sh_ac[NQ], sh_as[NQ], zsh[NQ];

    if (t < DEPTH * NQ) {
        float phi = w[t * 3 + 0], th = w[t * 3 + 1], om = w[t * 3 + 2];
        float ct = cosf(0.5f * th), sn = sinf(0.5f * th);
        float a0 = -0.5f * (phi + om);
        float a1 = 0.5f * (phi - om);
        float c0 = cosf(a0), s0 = sinf(a0);
        float c1 = cosf(a1), s1 = sinf(a1);
        float m00r = c0 * ct,  m00i = s0 * ct;
        float m01r = -c1 * sn, m01i = -s1 * sn;
        float m10r = c1 * sn,  m10i = -s1 * sn;
        float m11r = c0 * ct,  m11i = -s0 * ct;
        mcoef[t][0] = v2f{m00r, m00i};  mcoef[t][1] = v2f{-m00i, m00r};
        mcoef[t][2] = v2f{m01r, m01i};  mcoef[t][3] = v2f{-m01i, m01r};
        mcoef[t][4] = v2f{m11r, m11i};  mcoef[t][5] = v2f{-m11i, m11r};
        mcoef[t][6] = v2f{m10r, m10i};  mcoef[t][7] = v2f{-m10i, m10r};
    }
    // merged wave-gate builder: thread t<64 computes entry (a=row wave, bw=col wave)
    if (t < 64) {
        const int a = t >> 3, bw = t & 7;
        #pragma unroll
        for (int l = 0; l < DEPTH; ++l) {
            float ur = 1.f, ui = 0.f;
            #pragma unroll
            for (int j = 0; j < 3; ++j) {          // wave wires 0,1,2
                const int g = (l * NQ + j) * 3;
                float phi = w[g + 0], th = w[g + 1], om = w[g + 2];
                float ct = cosf(0.5f * th), sn = sinf(0.5f * th);
                const int ab = (a >> (2 - j)) & 1;   // row bit for wire j
                const int bb = (bw >> (2 - j)) & 1;  // col bit for wire j
                float ang, mag;
                if (ab == 0 && bb == 0)      { ang = -0.5f * (phi + om); mag = ct; }
                else if (ab == 0)            { ang =  0.5f * (phi - om); mag = -sn; }
                else if (bb == 0)            { ang = -0.5f * (phi - om); mag = sn; }
                else                         { ang =  0.5f * (phi + om); mag = ct; }
                float mr = mag * cosf(ang), mi = mag * sinf(ang);
                float nr = ur * mr - ui * mi, ni = ur * mi + ui * mr;
                ur = nr; ui = ni;
            }
            uA[l][a][bw] = v2f{ur, ui};
            uB[l][a][bw] = v2f{-ui, ur};
        }
    }

    // ---------------- projection: wave v owns q=v (waves 0-3 also q=v+8) ----
    {
        const float2* x2  = reinterpret_cast<const float2*>(x + (size_t)b * FEAT);
        const float2* Wp2 = reinterpret_cast<const float2*>(Wp);
        float2 xv[6];
        #pragma unroll
        for (int c = 0; c < 6; ++c) xv[c] = x2[lane + 64 * c];
        float accA = 0.f;
        #pragma unroll
        for (int c = 0; c < 6; ++c) {
            float2 wv = Wp2[wave * 384 + lane + 64 * c];
            accA += xv[c].x * wv.x + xv[c].y * wv.y;
        }
        accA = allred(accA);
        float accB = 0.f;
        if (wave < 4) {
            #pragma unroll
            for (int c = 0; c < 6; ++c) {
                float2 wv = Wp2[(wave + 8) * 384 + lane + 64 * c];
                accB += xv[c].x * wv.x + xv[c].y * wv.y;
            }
            accB = allred(accB);
        }
        if (lane == 0) {
            sh_dot[wave] = accA;
            if (wave < 4) sh_dot[wave + 8] = accB;
        }
    }
    __syncthreads();
    if (t < NQ) {
        float h = 0.5f * (tanhf(sh_dot[t]) * PI_HALF);
        sh_ac[t] = cosf(h);
        sh_as[t] = sinf(h);
    }
    __syncthreads();

    // ---------------- direct product-state init ----------------
    int lw = wave;     // logical wave: wire0=lw&4, wire1=lw&2, wire2=lw&1
    float pr[AMPS];
    float L = ((wave & 4) ? sh_as[0] : sh_ac[0]);
    L *= (wave & 2) ? sh_as[1] : sh_ac[1];
    L *= (wave & 1) ? sh_as[2] : sh_ac[2];
    L *= (lane & 32) ? sh_as[3] : sh_ac[3];
    L *= (lane & 16) ? sh_as[4] : sh_ac[4];
    L *= (lane &  8) ? sh_as[5] : sh_ac[5];
    L *= (lane &  4) ? sh_as[6] : sh_ac[6];
    L *= (lane &  2) ? sh_as[7] : sh_ac[7];
    L *= (lane &  1) ? sh_as[8] : sh_ac[8];
    pr[0] = L;
    #pragma unroll
    for (int wbit = 0; wbit < 3; ++wbit) {       // wire = 11-wbit
        const int bmask = 1 << wbit;
        const float cw = sh_ac[11 - wbit], sw = sh_as[11 - wbit];
        #pragma unroll
        for (int j = 0; j < AMPS; ++j) {
            if (j < bmask) {
                pr[j | bmask] = pr[j] * sw;
                pr[j] = pr[j] * cw;
            }
        }
    }
    v2f z[AMPS];
    #pragma unroll
    for (int j = 0; j < AMPS; ++j) z[j] = v2f{pr[j], 0.f};

    // ---------------- StronglyEntanglingLayers ----------------
    // ----- layer 0 -----
    {
        const v2f* mb = &mcoef[0 * NQ][0];
        wave3<0>(z, uA[0], uB[0], ex, lw, lane);    // wires 0,1,2 merged
        rot_lane<32>(z, mb + 3 * 8, lane);          // wire 3
        rot_lane<16>(z, mb + 4 * 8, lane);          // wire 4
        rot_lane< 8>(z, mb + 5 * 8, lane);          // wire 5
        rot_lane< 4>(z, mb + 6 * 8, lane);          // wire 6
        rot_lane< 2>(z, mb + 7 * 8, lane);          // wire 7
        rot_lane< 1>(z, mb + 8 * 8, lane);          // wire 8
        rot_reg < 4>(z, mb + 9 * 8);                // wire 9
        rot_reg < 2>(z, mb + 10 * 8);               // wire 10
        rot_reg < 1>(z, mb + 11 * 8);               // wire 11
        // CNOT ring r=1 (exchange CNOT(11,0) folded into next wave3 read):
        lw ^= (lw & 4) ? 2 : 0;          // (0,1): relabel
        lw ^= (lw & 2) ? 1 : 0;          // (1,2): relabel
        cnot_wl< 1, 32>(z, lw);          // (2,3)
        cnot_ll<32, 16>(z, lane);        // (3,4)
        cnot_ll<16,  8>(z, lane);        // (4,5)
        cnot_ll< 8,  4>(z, lane);        // (5,6)
        cnot_ll< 4,  2>(z, lane);        // (6,7)
        cnot_ll< 2,  1>(z, lane);        // (7,8)
        cnot_lr< 1,  4>(z, lane);        // (8,9)
        cnot_rr< 4,  2>(z);              // (9,10)
        cnot_rr< 2,  1>(z);              // (10,11)
    }
    // ----- layer 1 -----
    {
        const v2f* mb = &mcoef[1 * NQ][0];
        wave3<1>(z, uA[1], uB[1], ex, lw, lane);    // wires 0,1,2 (+ folded CNOT(11,0))
        rot_lane<32>(z, mb + 3 * 8, lane);
        rot_lane<16>(z, mb + 4 * 8, lane);
        rot_lane< 8>(z, mb + 5 * 8, lane);
        rot_lane< 4>(z, mb + 6 * 8, lane);
        rot_lane< 2>(z, mb + 7 * 8, lane);
        rot_lane< 1>(z, mb + 8 * 8, lane);
        rot_reg < 4>(z, mb + 9 * 8);
        rot_reg < 2>(z, mb + 10 * 8);
        rot_reg < 1>(z, mb + 11 * 8);
        // CNOT ring r=2 (exchange CNOT(10,0)+(11,1) folded into next wave3):
        lw ^= (lw & 4) ? 1 : 0;          // (0,2): relabel
        cnot_wl< 2, 32>(z, lw);          // (1,3)
        cnot_wl< 1, 16>(z, lw);          // (2,4)
        cnot_ll<32,  8>(z, lane);        // (3,5)
        cnot_ll<16,  4>(z, lane);        // (4,6)
        cnot_ll< 8,  2>(z, lane);        // (5,7)
        cnot_ll< 4,  1>(z, lane);        // (6,8)
        cnot_lr< 2,  4>(z, lane);        // (7,9)
        cnot_lr< 1,  2>(z, lane);        // (8,10)
        cnot_rr< 4,  1>(z);              // (9,11)
    }
    // ----- layer 2 -----
    {
        const v2f* mb = &mcoef[2 * NQ][0];
        wave3<2>(z, uA[2], uB[2], ex, lw, lane);    // wires 0,1,2 (+ folded CNOTs)
        rot_lane<32>(z, mb + 3 * 8, lane);
        rot_lane<16>(z, mb + 4 * 8, lane);
        rot_lane< 8>(z, mb + 5 * 8, lane);
        rot_lane< 4>(z, mb + 6 * 8, lane);
        rot_lane< 2>(z, mb + 7 * 8, lane);
        rot_lane< 1>(z, mb + 8 * 8, lane);
        rot_reg < 4>(z, mb + 9 * 8);
        rot_reg < 2>(z, mb + 10 * 8);
        rot_reg < 1>(z, mb + 11 * 8);
        // CNOT ring r=3 absorbed into observables below (Heisenberg).
    }

    // ---------------- PauliZ expectations (conjugated through layer-2 CNOTs)
    // O0={3,6,9} O1={4,7,10} O2={5,8,11} O3={0,3} O4={1,4} O5={2,5}
    // O6={0,3,6} O7={1,4,7} O8={2,5,8} O9={0,3,6,9} O10={1,4,7,10} O11={2,5,8,11}
    float ptot = 0.f, zn4 = 0.f, zn2 = 0.f, zn1 = 0.f;
    #pragma unroll
    for (int j = 0; j < AMPS; ++j) {
        float p = z[j].x * z[j].x + z[j].y * z[j].y;
        ptot += p;
        if (j & 4) zn4 += p;
        if (j & 2) zn2 += p;
        if (j & 1) zn1 += p;
    }
    const float s4 = ptot - 2.f * zn4;   // wire 9 sign (j&4)
    const float s2 = ptot - 2.f * zn2;   // wire 10 sign (j&2)
    const float s1 = ptot - 2.f * zn1;   // wire 11 sign (j&1)
    const bool p36 = ((lane >> 5) ^ (lane >> 2)) & 1;   // parity wires {3,6}
    const bool p18 = ((lane >> 4) ^ (lane >> 1)) & 1;   // parity wires {4,7}
    const bool p9  = ((lane >> 3) ^ lane) & 1;          // parity wires {5,8}

    const float a0 = allred(p36 ? -s4 : s4);            // O0 / O9 base
    const float a1 = allred(p18 ? -s2 : s2);            // O1 / O10 base
    const float a2 = allred(p9  ? -s1 : s1);            // O2 / O11 base
    const float a3 = allred((lane & 32) ? -ptot : ptot);// O3 base
    const float a4 = allred((lane & 16) ? -ptot : ptot);// O4 base
    const float a5 = allred((lane &  8) ? -ptot : ptot);// O5 base
    const float a6 = allred(p36 ? -ptot : ptot);        // O6 base
    const float a7 = allred(p18 ? -ptot : ptot);        // O7 base
    const float a8 = allred(p9  ? -ptot : ptot);        // O8 base

    const float w0s = (lw & 4) ? -1.f : 1.f;
    const float w1s = (lw & 2) ? -1.f : 1.f;
    const float w2s = (lw & 1) ? -1.f : 1.f;
    float zp[NQ];
    zp[0]  = a0;        zp[1]  = a1;        zp[2]  = a2;
    zp[3]  = w0s * a3;  zp[4]  = w1s * a4;  zp[5]  = w2s * a5;
    zp[6]  = w0s * a6;  zp[7]  = w1s * a7;  zp[8]  = w2s * a8;
    zp[9]  = w0s * a0;  zp[10] = w1s * a1;  zp[11] = w2s * a2;

    if (lane == 0) {
        #pragma unroll
        for (int q = 0; q < NQ; ++q) red[wave][q] = zp[q];
    }
    __syncthreads();
    if (t < NQ) {
        float s = 0.f;
        #pragma unroll
        for (int v = 0; v < NW; ++v) s += red[v][t];
        zsh[t] = s;
    }
    __syncthreads();

    // ---------------- output head ----------------
    if (t < NCLS) {
        float o = bo[t];
        #pragma unroll
        for (int q = 0; q < NQ; ++q) o = fmaf(zsh[q], Wo[t * NQ + q], o);
        out[(size_t)b * NCLS + t] = o;
    }
}

extern "C" void kernel_launch(void* const* d_in, const int* in_sizes, int n_in,
                              void* d_out, int out_size, void* d_ws, size_t ws_size,
                              hipStream_t stream) {
    const float* x  = (const float*)d_in[0];   // [B,768]
    const float* Wp = (const float*)d_in[1];   // [12,768]
    const float* w  = (const float*)d_in[2];   // [3,12,3]
    const float* Wo = (const float*)d_in[3];   // [10,12]
    const float* bo = (const float*)d_in[4];   // [10]
    float* out = (float*)d_out;

    const int B = in_sizes[0] / FEAT;          // 4096
    qcircuit_k8<<<B, 512, 0, stream>>>(x, Wp, w, Wo, bo, out);
}

// Round 13
// 155.297 us; speedup vs baseline: 1.9746x; 1.9746x over previous
//
#include <hip/hip_runtime.h>
#include <math.h>

#define NQ 12
#define DEPTH 3
#define FEAT 768
#define NCLS 10
#define NW 8                 // waves per block
#define AMPS 8               // complex amps per thread
#define PI_HALF 1.57079632679489662f

typedef float v2f __attribute__((ext_vector_type(2)));

// ---------- packed complex helpers (VOP3P packed fp32) ----------
__device__ __forceinline__ v2f pk_mul_bl(v2f A, v2f z) {
    v2f d;
    asm("v_pk_mul_f32 %0, %1, %2 op_sel:[0,0] op_sel_hi:[1,0]"
        : "=v"(d) : "v"(A), "v"(z));
    return d;
}
__device__ __forceinline__ void pk_fma_bl(v2f& d, v2f A, v2f z) {
    asm("v_pk_fma_f32 %0, %1, %2, %0 op_sel:[0,0,0] op_sel_hi:[1,0,1]"
        : "+v"(d) : "v"(A), "v"(z));
}
__device__ __forceinline__ void pk_fma_bh(v2f& d, v2f B, v2f z) {
    asm("v_pk_fma_f32 %0, %1, %2, %0 op_sel:[0,1,0] op_sel_hi:[1,1,1]"
        : "+v"(d) : "v"(B), "v"(z));
}
// z' = S*z + P*p (complex): As={sr,si} Bs={-si,sr} Ap={pr,pi} Bp={-pi,pr}
__device__ __forceinline__ v2f cgate(v2f As, v2f Bs, v2f Ap, v2f Bp, v2f z, v2f p) {
    v2f d = pk_mul_bl(As, z);
    pk_fma_bh(d, Bs, z);
    pk_fma_bl(d, Ap, p);
    pk_fma_bh(d, Bp, p);
    return d;
}

// ---------- lane-swap helpers ----------
#define DPPF(v, ctrl) __int_as_float(__builtin_amdgcn_update_dpp(0, __float_as_int(v), (ctrl), 0xF, 0xF, true))

template<int M>
__device__ __forceinline__ float swx(float v) {
    if constexpr (M == 1) {
        return DPPF(v, 0xB1);
    } else if constexpr (M == 2) {
        return DPPF(v, 0x4E);
    } else if constexpr (M == 4) {
        float t = DPPF(v, 0x141);
        return DPPF(t, 0x1B);
    } else if constexpr (M == 8) {
        return DPPF(v, 0x128);
    } else if constexpr (M == 16) {
        return __int_as_float(__builtin_amdgcn_ds_swizzle(__float_as_int(v), 0x401F));
    } else {
        return __shfl_xor(v, 32, 64);
    }
}

template<int M>
__device__ __forceinline__ v2f swx2(v2f z) {
    v2f p;
    p.x = swx<M>(z.x);
    p.y = swx<M>(z.y);
    return p;
}

__device__ __forceinline__ float allred(float v) {
    v += swx<1>(v); v += swx<2>(v); v += swx<4>(v);
    v += swx<8>(v); v += swx<16>(v); v += swx<32>(v);
    return v;
}

// ---------- state layouts ----------
// amp index i (bit11..bit0), wire q <-> bit (11-q).  Lane always: wire3=lane&32,
// wire4=lane&16, wire5=lane&8, wire6=lane&4, wire7=lane&2, wire8=lane&1.
// Layout A: wave=wires0-2 (lw bit2=w0,bit1=w1,bit0=w2); reg=wires9-11 (j&4=w9,j&2=w10,j&1=w11).
// Layout B: wave=wires9-11 (lw bit2=w9,...); reg=wires0-2 (j&4=w0, j&2=w1, j&1=w2).
// Relayout (transpose wave-field <-> reg-field): z_new[k] = ex[k][lw][lane]. Symmetric.

template<int JM>
__device__ __forceinline__ void rot_reg(v2f (&z)[AMPS], const v2f* m) {
    const v2f A0 = m[0], B0 = m[1], P0 = m[2], Q0 = m[3];
    const v2f A1 = m[4], B1 = m[5], P1 = m[6], Q1 = m[7];
    #pragma unroll
    for (int j = 0; j < AMPS; ++j) if (!(j & JM)) {
        const int j1 = j | JM;
        v2f z0 = z[j], z1 = z[j1];
        z[j]  = cgate(A0, B0, P0, Q0, z0, z1);
        z[j1] = cgate(A1, B1, P1, Q1, z1, z0);
    }
}

template<int LM>
__device__ __forceinline__ void rot_lane(v2f (&z)[AMPS], const v2f* m, int lane) {
    const bool b = (lane & LM) != 0;
    const v2f As = b ? m[4] : m[0], Bs = b ? m[5] : m[1];
    const v2f Ap = b ? m[6] : m[2], Bp = b ? m[7] : m[3];
    #pragma unroll
    for (int j = 0; j < AMPS; ++j) {
        v2f p = swx2<LM>(z[j]);
        z[j] = cgate(As, Bs, Ap, Bp, z[j], p);
    }
}

// transpose wave-field <-> reg-field (A<->B), 1 exchange pass
__device__ __forceinline__ void relayout(v2f (&z)[AMPS], v2f (*ex)[AMPS][64], int lw, int lane) {
    #pragma unroll
    for (int k = 0; k < AMPS; ++k) ex[lw][k][lane] = z[k];
    __syncthreads();
    #pragma unroll
    for (int k = 0; k < AMPS; ++k) z[k] = ex[k][lw][lane];
    __syncthreads();
}

// CNOT(8,9) in layout B: ctrl lane&1, tgt lw&4
__device__ __forceinline__ void exch_89(v2f (&z)[AMPS], v2f (*ex)[AMPS][64], int lw, int lane) {
    #pragma unroll
    for (int k = 0; k < AMPS; ++k) ex[lw][k][lane] = z[k];
    __syncthreads();
    if (lane & 1) {
        #pragma unroll
        for (int k = 0; k < AMPS; ++k) z[k] = ex[lw ^ 4][k][lane];
    }
    __syncthreads();
}

// CNOT(10,0)+CNOT(11,1) in layout A: ctrl j&2->tgt lw&4, ctrl j&1->tgt lw&2
__device__ __forceinline__ void exch_10_11(v2f (&z)[AMPS], v2f (*ex)[AMPS][64], int lw, int lane) {
    #pragma unroll
    for (int k = 0; k < AMPS; ++k) ex[lw][k][lane] = z[k];
    __syncthreads();
    #pragma unroll
    for (int k = 0; k < AMPS; ++k) {
        const int so = (k & 3) << 1;
        if (so) z[k] = ex[lw ^ so][k][lane];
    }
    __syncthreads();
}

template<int JC, int JT>
__device__ __forceinline__ void cnot_rr(v2f (&z)[AMPS]) {
    #pragma unroll
    for (int j = 0; j < AMPS; ++j) if ((j & JC) && !(j & JT)) {
        const int j1 = j | JT;
        v2f t = z[j]; z[j] = z[j1]; z[j1] = t;
    }
}

template<int JC, int LT>
__device__ __forceinline__ void cnot_rl(v2f (&z)[AMPS]) {
    #pragma unroll
    for (int j = 0; j < AMPS; ++j) if (j & JC) z[j] = swx2<LT>(z[j]);
}

template<int LC, int JT>
__device__ __forceinline__ void cnot_lr(v2f (&z)[AMPS], int lane) {
    const bool b = (lane & LC) != 0;
    #pragma unroll
    for (int j = 0; j < AMPS; ++j) if (!(j & JT)) {
        const int j1 = j | JT;
        v2f z0 = z[j], z1 = z[j1];
        z[j]  = b ? z1 : z0;
        z[j1] = b ? z0 : z1;
    }
}

template<int LC, int LT>
__device__ __forceinline__ void cnot_ll(v2f (&z)[AMPS], int lane) {
    const bool b = (lane & LC) != 0;
    #pragma unroll
    for (int j = 0; j < AMPS; ++j) {
        v2f p = swx2<LT>(z[j]);
        z[j] = b ? p : z[j];
    }
}

template<int PC, int LT>
__device__ __forceinline__ void cnot_wl(v2f (&z)[AMPS], int lw) {
    if (lw & PC) {                      // wave-uniform branch
        #pragma unroll
        for (int j = 0; j < AMPS; ++j) z[j] = swx2<LT>(z[j]);
    }
}

template<int PC, int JT>
__device__ __forceinline__ void cnot_wr(v2f (&z)[AMPS], int lw) {
    if (lw & PC) {                      // wave-uniform reg swap
        #pragma unroll
        for (int j = 0; j < AMPS; ++j) if (!(j & JT)) {
            const int j1 = j | JT;
            v2f t = z[j]; z[j] = z[j1]; z[j1] = t;
        }
    }
}

// Block = 1 sample, 8 waves x 64 lanes x 8 amps = 4096 amps.
// Alternating A/B layouts: ONE relayout per layer turns all wave-wire Rots
// into register gates; only 1 genuine cross-wave CNOT exchange per ring
// (layers 0,1); layer-2 ring Heisenberg-absorbed into observables.
__global__ __launch_bounds__(512) void qcircuit_rl(
    const float* __restrict__ x,    // [B, 768]
    const float* __restrict__ Wp,   // [12, 768]
    const float* __restrict__ w,    // [3, 12, 3]
    const float* __restrict__ Wo,   // [10, 12]
    const float* __restrict__ bo,   // [10]
    float* __restrict__ out)        // [B, 10]
{
    const int t = threadIdx.x;
    const int wave = t >> 6;
    const int lane = t & 63;
    const int b = blockIdx.x;

    __shared__ v2f mcoef[DEPTH * NQ][8];   // packed gate coefficients
    __shared__ v2f ex[NW][AMPS][64];       // 32 KB exchange buffer
    __shared__ float red[NW][NQ];
    __shared__ float sh_dot[NQ];
    __shared__ float sh_ac[NQ], sh_as[NQ], zsh[NQ];

    if (t < DEPTH * NQ) {
        float phi = w[t * 3 + 0], th = w[t * 3 + 1], om = w[t * 3 + 2];
        float ct = cosf(0.5f * th), sn = sinf(0.5f * th);
        float a0 = -0.5f * (phi + om);
        float a1 = 0.5f * (phi - om);
        float c0 = cosf(a0), s0 = sinf(a0);
        float c1 = cosf(a1), s1 = sinf(a1);
        float m00r = c0 * ct,  m00i = s0 * ct;
        float m01r = -c1 * sn, m01i = -s1 * sn;
        float m10r = c1 * sn,  m10i = -s1 * sn;
        float m11r = c0 * ct,  m11i = -s0 * ct;
        mcoef[t][0] = v2f{m00r, m00i};  mcoef[t][1] = v2f{-m00i, m00r};
        mcoef[t][2] = v2f{m01r, m01i};  mcoef[t][3] = v2f{-m01i, m01r};
        mcoef[t][4] = v2f{m11r, m11i};  mcoef[t][5] = v2f{-m11i, m11r};
        mcoef[t][6] = v2f{m10r, m10i};  mcoef[t][7] = v2f{-m10i, m10r};
    }

    // ---------------- projection: wave v owns q=v (waves 0-3 also q=v+8) ----
    {
        const float2* x2  = reinterpret_cast<const float2*>(x + (size_t)b * FEAT);
        const float2* Wp2 = reinterpret_cast<const float2*>(Wp);
        float2 xv[6];
        #pragma unroll
        for (int c = 0; c < 6; ++c) xv[c] = x2[lane + 64 * c];
        float accA = 0.f;
        #pragma unroll
        for (int c = 0; c < 6; ++c) {
            float2 wv = Wp2[wave * 384 + lane + 64 * c];
            accA += xv[c].x * wv.x + xv[c].y * wv.y;
        }
        accA = allred(accA);
        float accB = 0.f;
        if (wave < 4) {
            #pragma unroll
            for (int c = 0; c < 6; ++c) {
                float2 wv = Wp2[(wave + 8) * 384 + lane + 64 * c];
                accB += xv[c].x * wv.x + xv[c].y * wv.y;
            }
            accB = allred(accB);
        }
        if (lane == 0) {
            sh_dot[wave] = accA;
            if (wave < 4) sh_dot[wave + 8] = accB;
        }
    }
    __syncthreads();
    if (t < NQ) {
        float h = 0.5f * (tanhf(sh_dot[t]) * PI_HALF);
        sh_ac[t] = cosf(h);
        sh_as[t] = sinf(h);
    }
    __syncthreads();

    // ---------------- direct product-state init (layout A) ----------------
    int lw = wave;
    float pr[AMPS];
    float L = ((wave & 4) ? sh_as[0] : sh_ac[0]);
    L *= (wave & 2) ? sh_as[1] : sh_ac[1];
    L *= (wave & 1) ? sh_as[2] : sh_ac[2];
    L *= (lane & 32) ? sh_as[3] : sh_ac[3];
    L *= (lane & 16) ? sh_as[4] : sh_ac[4];
    L *= (lane &  8) ? sh_as[5] : sh_ac[5];
    L *= (lane &  4) ? sh_as[6] : sh_ac[6];
    L *= (lane &  2) ? sh_as[7] : sh_ac[7];
    L *= (lane &  1) ? sh_as[8] : sh_ac[8];
    pr[0] = L;
    #pragma unroll
    for (int wbit = 0; wbit < 3; ++wbit) {       // wire = 11-wbit (A: w9=j&4,w10=j&2,w11=j&1)
        const int bmask = 1 << wbit;
        const float cw = sh_ac[11 - wbit], sw = sh_as[11 - wbit];
        #pragma unroll
        for (int j = 0; j < AMPS; ++j) {
            if (j < bmask) {
                pr[j | bmask] = pr[j] * sw;
                pr[j] = pr[j] * cw;
            }
        }
    }
    v2f z[AMPS];
    #pragma unroll
    for (int j = 0; j < AMPS; ++j) z[j] = v2f{pr[j], 0.f};

    // ================ layer 0 (start in A) ================
    {
        const v2f* mb = &mcoef[0 * NQ][0];
        rot_reg < 4>(z, mb + 9 * 8);                // w9  (reg in A)
        rot_reg < 2>(z, mb + 10 * 8);               // w10
        rot_reg < 1>(z, mb + 11 * 8);               // w11
        rot_lane<32>(z, mb + 3 * 8, lane);          // w3
        rot_lane<16>(z, mb + 4 * 8, lane);          // w4
        rot_lane< 8>(z, mb + 5 * 8, lane);          // w5
        rot_lane< 4>(z, mb + 6 * 8, lane);          // w6
        rot_lane< 2>(z, mb + 7 * 8, lane);          // w7
        rot_lane< 1>(z, mb + 8 * 8, lane);          // w8
        relayout(z, ex, lw, lane);                  // A -> B
        rot_reg < 4>(z, mb + 0 * 8);                // w0  (reg in B)
        rot_reg < 2>(z, mb + 1 * 8);                // w1
        rot_reg < 1>(z, mb + 2 * 8);                // w2
        // ring r=1 in B (exact order):
        cnot_rr< 4,  2>(z);              // (0,1)
        cnot_rr< 2,  1>(z);              // (1,2)
        cnot_rl< 1, 32>(z);              // (2,3)
        cnot_ll<32, 16>(z, lane);        // (3,4)
        cnot_ll<16,  8>(z, lane);        // (4,5)
        cnot_ll< 8,  4>(z, lane);        // (5,6)
        cnot_ll< 4,  2>(z, lane);        // (6,7)
        cnot_ll< 2,  1>(z, lane);        // (7,8)
        exch_89(z, ex, lw, lane);        // (8,9)
        lw ^= (lw & 4) ? 2 : 0;          // (9,10) relabel
        lw ^= (lw & 2) ? 1 : 0;          // (10,11) relabel
        cnot_wr< 1,  4>(z, lw);          // (11,0)
    }
    // ================ layer 1 (in B) ================
    {
        const v2f* mb = &mcoef[1 * NQ][0];
        rot_reg < 4>(z, mb + 0 * 8);                // w0 (reg in B)
        rot_reg < 2>(z, mb + 1 * 8);                // w1
        rot_reg < 1>(z, mb + 2 * 8);                // w2
        rot_lane<32>(z, mb + 3 * 8, lane);
        rot_lane<16>(z, mb + 4 * 8, lane);
        rot_lane< 8>(z, mb + 5 * 8, lane);
        rot_lane< 4>(z, mb + 6 * 8, lane);
        rot_lane< 2>(z, mb + 7 * 8, lane);
        rot_lane< 1>(z, mb + 8 * 8, lane);
        relayout(z, ex, lw, lane);                  // B -> A
        rot_reg < 4>(z, mb + 9 * 8);                // w9 (reg in A)
        rot_reg < 2>(z, mb + 10 * 8);               // w10
        rot_reg < 1>(z, mb + 11 * 8);               // w11
        // ring r=2 in A (exact order):
        lw ^= (lw & 4) ? 1 : 0;          // (0,2) relabel
        cnot_wl< 2, 32>(z, lw);          // (1,3)
        cnot_wl< 1, 16>(z, lw);          // (2,4)
        cnot_ll<32,  8>(z, lane);        // (3,5)
        cnot_ll<16,  4>(z, lane);        // (4,6)
        cnot_ll< 8,  2>(z, lane);        // (5,7)
        cnot_ll< 4,  1>(z, lane);        // (6,8)
        cnot_lr< 2,  4>(z, lane);        // (7,9)
        cnot_lr< 1,  2>(z, lane);        // (8,10)
        cnot_rr< 4,  1>(z);              // (9,11)
        exch_10_11(z, ex, lw, lane);     // (10,0)+(11,1)
    }
    // ================ layer 2 (in A) ================
    {
        const v2f* mb = &mcoef[2 * NQ][0];
        rot_reg < 4>(z, mb + 9 * 8);                // w9 (reg in A)
        rot_reg < 2>(z, mb + 10 * 8);               // w10
        rot_reg < 1>(z, mb + 11 * 8);               // w11
        rot_lane<32>(z, mb + 3 * 8, lane);
        rot_lane<16>(z, mb + 4 * 8, lane);
        rot_lane< 8>(z, mb + 5 * 8, lane);
        rot_lane< 4>(z, mb + 6 * 8, lane);
        rot_lane< 2>(z, mb + 7 * 8, lane);
        rot_lane< 1>(z, mb + 8 * 8, lane);
        relayout(z, ex, lw, lane);                  // A -> B
        rot_reg < 4>(z, mb + 0 * 8);                // w0 (reg in B)
        rot_reg < 2>(z, mb + 1 * 8);                // w1
        rot_reg < 1>(z, mb + 2 * 8);                // w2
        // ring r=3 absorbed into observables (Heisenberg).
    }

    // ---------------- PauliZ expectations (layout B; conjugated masks) ------
    // B: w0=j&4 w1=j&2 w2=j&1; w3..w8 = lane bits; w9=lw&4 w10=lw&2 w11=lw&1.
    // O0={3,6,9} O1={4,7,10} O2={5,8,11} O3={0,3} O4={1,4} O5={2,5}
    // O6={0,3,6} O7={1,4,7} O8={2,5,8} O9={0,3,6,9} O10={1,4,7,10} O11={2,5,8,11}
    float ptot = 0.f, zn4 = 0.f, zn2 = 0.f, zn1 = 0.f;
    #pragma unroll
    for (int j = 0; j < AMPS; ++j) {
        float p = z[j].x * z[j].x + z[j].y * z[j].y;
        ptot += p;
        if (j & 4) zn4 += p;
        if (j & 2) zn2 += p;
        if (j & 1) zn1 += p;
    }
    const float S4 = ptot - 2.f * zn4;   // w0 sign (j&4)
    const float S2 = ptot - 2.f * zn2;   // w1 sign (j&2)
    const float S1 = ptot - 2.f * zn1;   // w2 sign (j&1)
    const bool p36 = ((lane >> 5) ^ (lane >> 2)) & 1;   // parity {w3,w6}
    const bool p18 = ((lane >> 4) ^ (lane >> 1)) & 1;   // parity {w4,w7}
    const bool p9  = ((lane >> 3) ^ lane) & 1;          // parity {w5,w8}

    const float a0 = allred(p36 ? -ptot : ptot);        // O0 base
    const float a1 = allred(p18 ? -ptot : ptot);        // O1 base
    const float a2 = allred(p9  ? -ptot : ptot);        // O2 base
    const float a3 = allred((lane & 32) ? -S4 : S4);    // O3
    const float a4 = allred((lane & 16) ? -S2 : S2);    // O4
    const float a5 = allred((lane &  8) ? -S1 : S1);    // O5
    const float a6 = allred(p36 ? -S4 : S4);            // O6 / O9 base
    const float a7 = allred(p18 ? -S2 : S2);            // O7 / O10 base
    const float a8 = allred(p9  ? -S1 : S1);            // O8 / O11 base

    const float W9  = (lw & 4) ? -1.f : 1.f;
    const float W10 = (lw & 2) ? -1.f : 1.f;
    const float W11 = (lw & 1) ? -1.f : 1.f;
    float zp[NQ];
    zp[0]  = W9 * a0;   zp[1]  = W10 * a1;  zp[2]  = W11 * a2;
    zp[3]  = a3;        zp[4]  = a4;        zp[5]  = a5;
    zp[6]  = a6;        zp[7]  = a7;        zp[8]  = a8;
    zp[9]  = W9 * a6;   zp[10] = W10 * a7;  zp[11] = W11 * a8;

    if (lane == 0) {
        #pragma unroll
        for (int q = 0; q < NQ; ++q) red[wave][q] = zp[q];
    }
    __syncthreads();
    if (t < NQ) {
        float s = 0.f;
        #pragma unroll
        for (int v = 0; v < NW; ++v) s += red[v][t];
        zsh[t] = s;
    }
    __syncthreads();

    // ---------------- output head ----------------
    if (t < NCLS) {
        float o = bo[t];
        #pragma unroll
        for (int q = 0; q < NQ; ++q) o = fmaf(zsh[q], Wo[t * NQ + q], o);
        out[(size_t)b * NCLS + t] = o;
    }
}

extern "C" void kernel_launch(void* const* d_in, const int* in_sizes, int n_in,
                              void* d_out, int out_size, void* d_ws, size_t ws_size,
                              hipStream_t stream) {
    const float* x  = (const float*)d_in[0];   // [B,768]
    const float* Wp = (const float*)d_in[1];   // [12,768]
    const float* w  = (const float*)d_in[2];   // [3,12,3]
    const float* Wo = (const float*)d_in[3];   // [10,12]
    const float* bo = (const float*)d_in[4];   // [10]
    float* out = (float*)d_out;

    const int B = in_sizes[0] / FEAT;          // 4096
    qcircuit_rl<<<B, 512, 0, stream>>>(x, Wp, w, Wo, bo, out);
}

// Round 14
// 128.920 us; speedup vs baseline: 2.3786x; 1.2046x over previous
//
#include <hip/hip_runtime.h>
#include <math.h>

#define NQ 12
#define DEPTH 3
#define FEAT 768
#define NCLS 10
#define NW 8                 // waves per block
#define AMPS 8               // complex amps per thread
#define PI_HALF 1.57079632679489662f

typedef float v2f __attribute__((ext_vector_type(2)));

// ---------- packed complex helpers (VOP3P packed fp32) ----------
__device__ __forceinline__ v2f pk_mul_bl(v2f A, v2f z) {
    v2f d;
    asm("v_pk_mul_f32 %0, %1, %2 op_sel:[0,0] op_sel_hi:[1,0]"
        : "=v"(d) : "v"(A), "v"(z));
    return d;
}
__device__ __forceinline__ void pk_fma_bl(v2f& d, v2f A, v2f z) {
    asm("v_pk_fma_f32 %0, %1, %2, %0 op_sel:[0,0,0] op_sel_hi:[1,0,1]"
        : "+v"(d) : "v"(A), "v"(z));
}
__device__ __forceinline__ void pk_fma_bh(v2f& d, v2f B, v2f z) {
    asm("v_pk_fma_f32 %0, %1, %2, %0 op_sel:[0,1,0] op_sel_hi:[1,1,1]"
        : "+v"(d) : "v"(B), "v"(z));
}
// z' = S*z + P*p (complex): As={sr,si} Bs={-si,sr} Ap={pr,pi} Bp={-pi,pr}
__device__ __forceinline__ v2f cgate(v2f As, v2f Bs, v2f Ap, v2f Bp, v2f z, v2f p) {
    v2f d = pk_mul_bl(As, z);
    pk_fma_bh(d, Bs, z);
    pk_fma_bl(d, Ap, p);
    pk_fma_bh(d, Bp, p);
    return d;
}

// ---------- lane-swap helpers ----------
#define DPPF(v, ctrl) __int_as_float(__builtin_amdgcn_update_dpp(0, __float_as_int(v), (ctrl), 0xF, 0xF, true))

template<int M>
__device__ __forceinline__ float swx(float v) {
    if constexpr (M == 1) {
        return DPPF(v, 0xB1);
    } else if constexpr (M == 2) {
        return DPPF(v, 0x4E);
    } else if constexpr (M == 4) {
        float t = DPPF(v, 0x141);
        return DPPF(t, 0x1B);
    } else if constexpr (M == 8) {
        return DPPF(v, 0x128);
    } else if constexpr (M == 16) {
        return __int_as_float(__builtin_amdgcn_ds_swizzle(__float_as_int(v), 0x401F));
    } else {
        return __shfl_xor(v, 32, 64);
    }
}

template<int M>
__device__ __forceinline__ v2f swx2(v2f z) {
    v2f p;
    p.x = swx<M>(z.x);
    p.y = swx<M>(z.y);
    return p;
}

__device__ __forceinline__ float allred(float v) {
    v += swx<1>(v); v += swx<2>(v); v += swx<4>(v);
    v += swx<8>(v); v += swx<16>(v); v += swx<32>(v);
    return v;
}

// ---------- state layouts ----------
// amp index i (bit11..bit0), wire q <-> bit (11-q).  Lane always: wire3=lane&32,
// wire4=lane&16, wire5=lane&8, wire6=lane&4, wire7=lane&2, wire8=lane&1.
// Layout A: wave=wires0-2 (lw bit2=w0,bit1=w1,bit0=w2); reg=wires9-11 (j&4=w9,j&2=w10,j&1=w11).
// Layout B: wave=wires9-11 (lw bit2=w9,...); reg=wires0-2 (j&4=w0, j&2=w1, j&1=w2).

template<int JM>
__device__ __forceinline__ void rot_reg(v2f (&z)[AMPS], const v2f* m) {
    const v2f A0 = m[0], B0 = m[1], P0 = m[2], Q0 = m[3];
    const v2f A1 = m[4], B1 = m[5], P1 = m[6], Q1 = m[7];
    #pragma unroll
    for (int j = 0; j < AMPS; ++j) if (!(j & JM)) {
        const int j1 = j | JM;
        v2f z0 = z[j], z1 = z[j1];
        z[j]  = cgate(A0, B0, P0, Q0, z0, z1);
        z[j1] = cgate(A1, B1, P1, Q1, z1, z0);
    }
}

template<int LM>
__device__ __forceinline__ void rot_lane(v2f (&z)[AMPS], const v2f* m, int lane) {
    const bool b = (lane & LM) != 0;
    const v2f As = b ? m[4] : m[0], Bs = b ? m[5] : m[1];
    const v2f Ap = b ? m[6] : m[2], Bp = b ? m[7] : m[3];
    #pragma unroll
    for (int j = 0; j < AMPS; ++j) {
        v2f p = swx2<LM>(z[j]);
        z[j] = cgate(As, Bs, Ap, Bp, z[j], p);
    }
}

// transpose wave-field <-> reg-field (A<->B), 1 exchange pass
__device__ __forceinline__ void relayout(v2f (&z)[AMPS], v2f (*ex)[AMPS][64], int lw, int lane) {
    #pragma unroll
    for (int k = 0; k < AMPS; ++k) ex[lw][k][lane] = z[k];
    __syncthreads();
    #pragma unroll
    for (int k = 0; k < AMPS; ++k) z[k] = ex[k][lw][lane];
    __syncthreads();
}

template<int JC, int JT>
__device__ __forceinline__ void cnot_rr(v2f (&z)[AMPS]) {
    #pragma unroll
    for (int j = 0; j < AMPS; ++j) if ((j & JC) && !(j & JT)) {
        const int j1 = j | JT;
        v2f t = z[j]; z[j] = z[j1]; z[j1] = t;
    }
}

// Block = 1 sample, 8 waves x 64 lanes x 8 amps = 4096 amps.
// Alternating A/B layouts (1 relayout/layer); ENTIRE ring-CNOT block fused
// into the layer's LDS exchange read addresses (CNOTs are GF(2) index
// permutations); layer-2 ring Heisenberg-absorbed into observables.
__global__ __launch_bounds__(512) void qcircuit_fz(
    const float* __restrict__ x,    // [B, 768]
    const float* __restrict__ Wp,   // [12, 768]
    const float* __restrict__ w,    // [3, 12, 3]
    const float* __restrict__ Wo,   // [10, 12]
    const float* __restrict__ bo,   // [10]
    float* __restrict__ out)        // [B, 10]
{
    const int t = threadIdx.x;
    const int wave = t >> 6;
    const int lane = t & 63;
    const int b = blockIdx.x;

    __shared__ v2f mcoef[DEPTH * NQ][8];   // packed gate coefficients
    __shared__ v2f ex[NW][AMPS][64];       // 32 KB exchange buffer
    __shared__ float red[NW][NQ];
    __shared__ float sh_dot[NQ];
    __shared__ float sh_ac[NQ], sh_as[NQ], zsh[NQ];

    if (t < DEPTH * NQ) {
        float phi = w[t * 3 + 0], th = w[t * 3 + 1], om = w[t * 3 + 2];
        float ct = cosf(0.5f * th), sn = sinf(0.5f * th);
        float a0 = -0.5f * (phi + om);
        float a1 = 0.5f * (phi - om);
        float c0 = cosf(a0), s0 = sinf(a0);
        float c1 = cosf(a1), s1 = sinf(a1);
        float m00r = c0 * ct,  m00i = s0 * ct;
        float m01r = -c1 * sn, m01i = -s1 * sn;
        float m10r = c1 * sn,  m10i = -s1 * sn;
        float m11r = c0 * ct,  m11i = -s0 * ct;
        mcoef[t][0] = v2f{m00r, m00i};  mcoef[t][1] = v2f{-m00i, m00r};
        mcoef[t][2] = v2f{m01r, m01i};  mcoef[t][3] = v2f{-m01i, m01r};
        mcoef[t][4] = v2f{m11r, m11i};  mcoef[t][5] = v2f{-m11i, m11r};
        mcoef[t][6] = v2f{m10r, m10i};  mcoef[t][7] = v2f{-m10i, m10r};
    }

    // ---------------- projection: wave v owns q=v (waves 0-3 also q=v+8) ----
    {
        const float2* x2  = reinterpret_cast<const float2*>(x + (size_t)b * FEAT);
        const float2* Wp2 = reinterpret_cast<const float2*>(Wp);
        float2 xv[6];
        #pragma unroll
        for (int c = 0; c < 6; ++c) xv[c] = x2[lane + 64 * c];
        float accA = 0.f;
        #pragma unroll
        for (int c = 0; c < 6; ++c) {
            float2 wv = Wp2[wave * 384 + lane + 64 * c];
            accA += xv[c].x * wv.x + xv[c].y * wv.y;
        }
        accA = allred(accA);
        float accB = 0.f;
        if (wave < 4) {
            #pragma unroll
            for (int c = 0; c < 6; ++c) {
                float2 wv = Wp2[(wave + 8) * 384 + lane + 64 * c];
                accB += xv[c].x * wv.x + xv[c].y * wv.y;
            }
            accB = allred(accB);
        }
        if (lane == 0) {
            sh_dot[wave] = accA;
            if (wave < 4) sh_dot[wave + 8] = accB;
        }
    }
    __syncthreads();
    if (t < NQ) {
        float h = 0.5f * (tanhf(sh_dot[t]) * PI_HALF);
        sh_ac[t] = cosf(h);
        sh_as[t] = sinf(h);
    }
    __syncthreads();

    // ---------------- direct product-state init (layout A) ----------------
    int lw = wave;
    float pr[AMPS];
    float L0 = ((wave & 4) ? sh_as[0] : sh_ac[0]);
    L0 *= (wave & 2) ? sh_as[1] : sh_ac[1];
    L0 *= (wave & 1) ? sh_as[2] : sh_ac[2];
    L0 *= (lane & 32) ? sh_as[3] : sh_ac[3];
    L0 *= (lane & 16) ? sh_as[4] : sh_ac[4];
    L0 *= (lane &  8) ? sh_as[5] : sh_ac[5];
    L0 *= (lane &  4) ? sh_as[6] : sh_ac[6];
    L0 *= (lane &  2) ? sh_as[7] : sh_ac[7];
    L0 *= (lane &  1) ? sh_as[8] : sh_ac[8];
    pr[0] = L0;
    #pragma unroll
    for (int wbit = 0; wbit < 3; ++wbit) {       // wire = 11-wbit (A: w9=j&4,w10=j&2,w11=j&1)
        const int bmask = 1 << wbit;
        const float cw = sh_ac[11 - wbit], sw = sh_as[11 - wbit];
        #pragma unroll
        for (int j = 0; j < AMPS; ++j) {
            if (j < bmask) {
                pr[j | bmask] = pr[j] * sw;
                pr[j] = pr[j] * cw;
            }
        }
    }
    v2f z[AMPS];
    #pragma unroll
    for (int j = 0; j < AMPS; ++j) z[j] = v2f{pr[j], 0.f};

    // ================ layer 0 (start in A) ================
    {
        const v2f* mb = &mcoef[0 * NQ][0];
        rot_reg < 4>(z, mb + 9 * 8);                // w9  (reg in A)
        rot_reg < 2>(z, mb + 10 * 8);               // w10
        rot_reg < 1>(z, mb + 11 * 8);               // w11
        rot_lane<32>(z, mb + 3 * 8, lane);          // w3
        rot_lane<16>(z, mb + 4 * 8, lane);          // w4
        rot_lane< 8>(z, mb + 5 * 8, lane);          // w5
        rot_lane< 4>(z, mb + 6 * 8, lane);          // w6
        rot_lane< 2>(z, mb + 7 * 8, lane);          // w7
        rot_lane< 1>(z, mb + 8 * 8, lane);          // w8
        relayout(z, ex, lw, lane);                  // A -> B
        rot_reg < 4>(z, mb + 0 * 8);                // w0  (reg in B)
        rot_reg < 2>(z, mb + 1 * 8);                // w1
        rot_reg < 1>(z, mb + 2 * 8);                // w2
        // ---- ring r=1 in B, fused ----
        cnot_rr< 4,  2>(z);              // (0,1)  (register renames)
        cnot_rr< 2,  1>(z);              // (1,2)
        // (2,3),(3,4),(4,5),(5,6),(6,7),(7,8),(8,9),(11,0) fused into one LDS
        // pass; (9,10),(10,11) are lw relabels.  Index maps composed
        // innermost-first (reverse gate order):
        {
            const int woff = (lane & 1) << 2;        // (8,9): ctrl w8=lane&1, tgt w9=lw&4
            int Ls = lane;
            Ls ^= (Ls & 2) >> 1;                     // (7,8)
            Ls ^= (Ls & 4) >> 1;                     // (6,7)
            Ls ^= (Ls & 8) >> 1;                     // (5,6)
            Ls ^= (Ls & 16) >> 1;                    // (4,5)
            Ls ^= (Ls & 32) >> 1;                    // (3,4)
            int lw2 = lw ^ ((lw & 4) ? 2 : 0);       // (9,10) relabel
            lw2 ^= (lw2 & 2) ? 1 : 0;                // (10,11) relabel
            const int wlc = (lw2 & 1) << 2;          // (11,0): ctrl w11=lw2&1, tgt w0=j&4
            #pragma unroll
            for (int k = 0; k < AMPS; ++k) ex[lw][k][lane] = z[k];
            __syncthreads();
            #pragma unroll
            for (int k = 0; k < AMPS; ++k)
                z[k] = ex[lw ^ woff][k ^ wlc][Ls ^ ((k & 1) << 5)];  // (2,3): k&1 -> ^32
            __syncthreads();
            lw = lw2;
        }
    }
    // ================ layer 1 (in B) ================
    {
        const v2f* mb = &mcoef[1 * NQ][0];
        rot_reg < 4>(z, mb + 0 * 8);                // w0 (reg in B)
        rot_reg < 2>(z, mb + 1 * 8);                // w1
        rot_reg < 1>(z, mb + 2 * 8);                // w2
        rot_lane<32>(z, mb + 3 * 8, lane);
        rot_lane<16>(z, mb + 4 * 8, lane);
        rot_lane< 8>(z, mb + 5 * 8, lane);
        rot_lane< 4>(z, mb + 6 * 8, lane);
        rot_lane< 2>(z, mb + 7 * 8, lane);
        rot_lane< 1>(z, mb + 8 * 8, lane);
        relayout(z, ex, lw, lane);                  // B -> A
        rot_reg < 4>(z, mb + 9 * 8);                // w9 (reg in A)
        rot_reg < 2>(z, mb + 10 * 8);               // w10
        rot_reg < 1>(z, mb + 11 * 8);               // w11
        // ---- ring r=2 in A, fully fused into one LDS pass ----
        // (0,2) is an lw relabel; (1,3),(2,4),(3,5),(4,6),(5,7),(6,8),(7,9),
        // (8,10),(9,11),(10,0),(11,1) composed innermost-first:
        {
            lw ^= (lw & 4) >> 2;                     // (0,2) relabel
            int Ls = lane;
            Ls ^= (Ls & 4) >> 2;                     // (6,8)
            Ls ^= (Ls & 8) >> 2;                     // (5,7)
            Ls ^= (Ls & 16) >> 2;                    // (4,6)
            Ls ^= (Ls & 32) >> 2;                    // (3,5)
            const int klx = ((lane & 2) << 1) ^ ((lane & 1) << 1);  // (7,9),(8,10)
            #pragma unroll
            for (int k = 0; k < AMPS; ++k) ex[lw][k][lane] = z[k];
            __syncthreads();
            #pragma unroll
            for (int k = 0; k < AMPS; ++k) {
                const int LW = lw ^ ((k & 1) << 1) ^ ((k & 2) << 1);   // (11,1),(10,0)
                const int K  = k ^ ((k & 4) >> 2) ^ klx;               // (9,11),(8,10),(7,9)
                const int Lr = Ls ^ ((LW & 1) << 4) ^ ((LW & 2) << 4); // (2,4),(1,3)
                z[k] = ex[LW][K][Lr];
            }
            __syncthreads();
        }
    }
    // ================ layer 2 (in A) ================
    {
        const v2f* mb = &mcoef[2 * NQ][0];
        rot_reg < 4>(z, mb + 9 * 8);                // w9 (reg in A)
        rot_reg < 2>(z, mb + 10 * 8);               // w10
        rot_reg < 1>(z, mb + 11 * 8);               // w11
        rot_lane<32>(z, mb + 3 * 8, lane);
        rot_lane<16>(z, mb + 4 * 8, lane);
        rot_lane< 8>(z, mb + 5 * 8, lane);
        rot_lane< 4>(z, mb + 6 * 8, lane);
        rot_lane< 2>(z, mb + 7 * 8, lane);
        rot_lane< 1>(z, mb + 8 * 8, lane);
        relayout(z, ex, lw, lane);                  // A -> B
        rot_reg < 4>(z, mb + 0 * 8);                // w0 (reg in B)
        rot_reg < 2>(z, mb + 1 * 8);                // w1
        rot_reg < 1>(z, mb + 2 * 8);                // w2
        // ring r=3 absorbed into observables (Heisenberg).
    }

    // ---------------- PauliZ expectations (layout B; conjugated masks) ------
    // B: w0=j&4 w1=j&2 w2=j&1; w3..w8 = lane bits; w9=lw&4 w10=lw&2 w11=lw&1.
    // O0={3,6,9} O1={4,7,10} O2={5,8,11} O3={0,3} O4={1,4} O5={2,5}
    // O6={0,3,6} O7={1,4,7} O8={2,5,8} O9={0,3,6,9} O10={1,4,7,10} O11={2,5,8,11}
    float ptot = 0.f, zn4 = 0.f, zn2 = 0.f, zn1 = 0.f;
    #pragma unroll
    for (int j = 0; j < AMPS; ++j) {
        float p = z[j].x * z[j].x + z[j].y * z[j].y;
        ptot += p;
        if (j & 4) zn4 += p;
        if (j & 2) zn2 += p;
        if (j & 1) zn1 += p;
    }
    const float S4 = ptot - 2.f * zn4;   // w0 sign (j&4)
    const float S2 = ptot - 2.f * zn2;   // w1 sign (j&2)
    const float S1 = ptot - 2.f * zn1;   // w2 sign (j&1)
    const bool p36 = ((lane >> 5) ^ (lane >> 2)) & 1;   // parity {w3,w6}
    const bool p18 = ((lane >> 4) ^ (lane >> 1)) & 1;   // parity {w4,w7}
    const bool p9  = ((lane >> 3) ^ lane) & 1;          // parity {w5,w8}

    const float a0 = allred(p36 ? -ptot : ptot);        // O0 base
    const float a1 = allred(p18 ? -ptot : ptot);        // O1 base
    const float a2 = allred(p9  ? -ptot : ptot);        // O2 base
    const float a3 = allred((lane & 32) ? -S4 : S4);    // O3
    const float a4 = allred((lane & 16) ? -S2 : S2);    // O4
    const float a5 = allred((lane &  8) ? -S1 : S1);    // O5
    const float a6 = allred(p36 ? -S4 : S4);            // O6 / O9 base
    const float a7 = allred(p18 ? -S2 : S2);            // O7 / O10 base
    const float a8 = allred(p9  ? -S1 : S1);            // O8 / O11 base

    const float W9  = (lw & 4) ? -1.f : 1.f;
    const float W10 = (lw & 2) ? -1.f : 1.f;
    const float W11 = (lw & 1) ? -1.f : 1.f;
    float zp[NQ];
    zp[0]  = W9 * a0;   zp[1]  = W10 * a1;  zp[2]  = W11 * a2;
    zp[3]  = a3;        zp[4]  = a4;        zp[5]  = a5;
    zp[6]  = a6;        zp[7]  = a7;        zp[8]  = a8;
    zp[9]  = W9 * a6;   zp[10] = W10 * a7;  zp[11] = W11 * a8;

    if (lane == 0) {
        #pragma unroll
        for (int q = 0; q < NQ; ++q) red[wave][q] = zp[q];
    }
    __syncthreads();
    if (t < NQ) {
        float s = 0.f;
        #pragma unroll
        for (int v = 0; v < NW; ++v) s += red[v][t];
        zsh[t] = s;
    }
    __syncthreads();

    // ---------------- output head ----------------
    if (t < NCLS) {
        float o = bo[t];
        #pragma unroll
        for (int q = 0; q < NQ; ++q) o = fmaf(zsh[q], Wo[t * NQ + q], o);
        out[(size_t)b * NCLS + t] = o;
    }
}

extern "C" void kernel_launch(void* const* d_in, const int* in_sizes, int n_in,
                              void* d_out, int out_size, void* d_ws, size_t ws_size,
                              hipStream_t stream) {
    const float* x  = (const float*)d_in[0];   // [B,768]
    const float* Wp = (const float*)d_in[1];   // [12,768]
    const float* w  = (const float*)d_in[2];   // [3,12,3]
    const float* Wo = (const float*)d_in[3];   // [10,12]
    const float* bo = (const float*)d_in[4];   // [10]
    float* out = (float*)d_out;

    const int B = in_sizes[0] / FEAT;          // 4096
    qcircuit_fz<<<B, 512, 0, stream>>>(x, Wp, w, Wo, bo, out);
}